// Round 1
// baseline (500.010 us; speedup 1.0000x reference)
//
#include <hip/hip_runtime.h>

#define N_NODES 100000
#define N_EDGES 1600000
#define IN_F 25
#define OUT_F 50

// h = x @ W  (h in workspace)
__global__ void gcn_linear_kernel(const float* __restrict__ x,
                                  const float* __restrict__ W,
                                  float* __restrict__ h) {
    __shared__ float Ws[IN_F * OUT_F];
    for (int i = threadIdx.x; i < IN_F * OUT_F; i += blockDim.x)
        Ws[i] = W[i];
    __syncthreads();
    int idx = blockIdx.x * blockDim.x + threadIdx.x;
    if (idx >= N_NODES * OUT_F) return;
    int n = idx / OUT_F;
    int f = idx - n * OUT_F;
    const float* xr = x + (long long)n * IN_F;
    float acc = 0.f;
#pragma unroll
    for (int k = 0; k < IN_F; ++k)
        acc += xr[k] * Ws[k * OUT_F + f];
    h[idx] = acc;
}

// out[n,f] = b[f]  (accumulator starts at bias; d_out arrives poisoned)
__global__ void gcn_init_out_kernel(const float* __restrict__ b,
                                    float* __restrict__ out) {
    int idx = blockIdx.x * blockDim.x + threadIdx.x;
    if (idx >= N_NODES * OUT_F) return;
    out[idx] = b[idx % OUT_F];
}

// one thread per (edge, feature): out[dst,f] += h[src,f]
__global__ void gcn_scatter_kernel(const float* __restrict__ h,
                                   const int* __restrict__ ei,
                                   float* __restrict__ out) {
    long long idx = (long long)blockIdx.x * blockDim.x + threadIdx.x;
    if (idx >= (long long)N_EDGES * OUT_F) return;
    int e = (int)(idx / OUT_F);
    int f = (int)(idx - (long long)e * OUT_F);
    int src = ei[e];            // row 0: src
    int dst = ei[N_EDGES + e];  // row 1: dst
    atomicAdd(&out[(long long)dst * OUT_F + f], h[(long long)src * OUT_F + f]);
}

__global__ void gcn_relu_kernel(float* __restrict__ out) {
    int idx = blockIdx.x * blockDim.x + threadIdx.x;
    if (idx >= N_NODES * OUT_F) return;
    out[idx] = fmaxf(out[idx], 0.f);
}

extern "C" void kernel_launch(void* const* d_in, const int* in_sizes, int n_in,
                              void* d_out, int out_size, void* d_ws, size_t ws_size,
                              hipStream_t stream) {
    const float* x  = (const float*)d_in[0];
    const float* W  = (const float*)d_in[1];
    const float* b  = (const float*)d_in[2];
    const int*   ei = (const int*)d_in[3];   // [2, N_EDGES], int32
    float* out = (float*)d_out;
    float* h   = (float*)d_ws;               // N_NODES*OUT_F floats = 20 MB

    const int T = 256;
    const int n_out = N_NODES * OUT_F;                       // 5,000,000
    const long long n_scatter = (long long)N_EDGES * OUT_F;  // 80,000,000

    gcn_linear_kernel<<<(n_out + T - 1) / T, T, 0, stream>>>(x, W, h);
    gcn_init_out_kernel<<<(n_out + T - 1) / T, T, 0, stream>>>(b, out);
    gcn_scatter_kernel<<<(int)((n_scatter + T - 1) / T), T, 0, stream>>>(h, ei, out);
    gcn_relu_kernel<<<(n_out + T - 1) / T, T, 0, stream>>>(out);
}

// Round 2
// 399.624 us; speedup vs baseline: 1.2512x; 1.2512x over previous
//
#include <hip/hip_runtime.h>

#define N_NODES 100000
#define N_EDGES 1600000
#define IN_F 25
#define OUT_F 50

#define SCAN_CHUNK 512
#define SCAN_NB ((N_NODES + SCAN_CHUNK - 1) / SCAN_CHUNK)   // 196

// ---------- h = x @ W ----------
__global__ void gcn_linear_kernel(const float* __restrict__ x,
                                  const float* __restrict__ W,
                                  float* __restrict__ h) {
    __shared__ float Ws[IN_F * OUT_F];
    for (int i = threadIdx.x; i < IN_F * OUT_F; i += blockDim.x)
        Ws[i] = W[i];
    __syncthreads();
    int idx = blockIdx.x * blockDim.x + threadIdx.x;
    if (idx >= N_NODES * OUT_F) return;
    int n = idx / OUT_F;
    int f = idx - n * OUT_F;
    const float* xr = x + (long long)n * IN_F;
    float acc = 0.f;
#pragma unroll
    for (int k = 0; k < IN_F; ++k)
        acc += xr[k] * Ws[k * OUT_F + f];
    h[idx] = acc;
}

// ---------- CSR build: histogram of dst ----------
__global__ void gcn_hist_kernel(const int* __restrict__ ei, int* __restrict__ deg) {
    int e = blockIdx.x * blockDim.x + threadIdx.x;
    if (e >= N_EDGES) return;
    atomicAdd(&deg[ei[N_EDGES + e]], 1);
}

// ---------- scan phase 1: per-chunk sums ----------
__global__ void gcn_scan1_kernel(const int* __restrict__ deg, int* __restrict__ bsum) {
    __shared__ int s[256];
    int base = blockIdx.x * SCAN_CHUNK;
    int sum = 0;
    for (int k = 0; k < 2; ++k) {
        int i = base + threadIdx.x + k * 256;
        if (i < N_NODES) sum += deg[i];
    }
    s[threadIdx.x] = sum;
    __syncthreads();
    for (int off = 128; off > 0; off >>= 1) {
        if (threadIdx.x < off) s[threadIdx.x] += s[threadIdx.x + off];
        __syncthreads();
    }
    if (threadIdx.x == 0) bsum[blockIdx.x] = s[0];
}

// ---------- scan phase 2: exclusive scan of chunk sums (NB=196 <= 256) ----------
__global__ void gcn_scan2_kernel(const int* __restrict__ bsum, int* __restrict__ boff,
                                 int* __restrict__ row_off) {
    __shared__ int s[256];
    int tid = threadIdx.x;
    s[tid] = (tid < SCAN_NB) ? bsum[tid] : 0;
    __syncthreads();
    if (tid == 0) {
        int run = 0;
        for (int i = 0; i < SCAN_NB; ++i) { int v = s[i]; s[i] = run; run += v; }
        row_off[N_NODES] = N_EDGES;   // total is known
    }
    __syncthreads();
    if (tid < SCAN_NB) boff[tid] = s[tid];
}

// ---------- scan phase 3: exclusive scan within chunk + chunk offset ----------
__global__ void gcn_scan3_kernel(const int* __restrict__ deg, const int* __restrict__ boff,
                                 int* __restrict__ row_off) {
    __shared__ int s[SCAN_CHUNK];
    int tid = threadIdx.x;                 // block = 512 threads
    int i = blockIdx.x * SCAN_CHUNK + tid;
    int v = (i < N_NODES) ? deg[i] : 0;
    s[tid] = v;
    for (int off = 1; off < SCAN_CHUNK; off <<= 1) {
        __syncthreads();
        int t = (tid >= off) ? s[tid - off] : 0;
        __syncthreads();
        s[tid] += t;
    }
    __syncthreads();
    if (i < N_NODES) row_off[i] = boff[blockIdx.x] + s[tid] - v;  // exclusive
}

// ---------- CSR fill ----------
__global__ void gcn_fill_kernel(const int* __restrict__ ei,
                                const int* __restrict__ row_off,
                                int* __restrict__ fill_ctr,
                                int* __restrict__ col) {
    int e = blockIdx.x * blockDim.x + threadIdx.x;
    if (e >= N_EDGES) return;
    int src = ei[e];
    int dst = ei[N_EDGES + e];
    int p = row_off[dst] + atomicAdd(&fill_ctr[dst], 1);
    col[p] = src;
}

// ---------- aggregate: one wave per node, lane = feature; fused bias + relu ----------
__global__ void gcn_aggregate_kernel(const float* __restrict__ h,
                                     const int* __restrict__ row_off,
                                     const int* __restrict__ col,
                                     const float* __restrict__ b,
                                     float* __restrict__ out) {
    int node = blockIdx.x * 4 + (threadIdx.x >> 6);   // 4 waves/block
    int f = threadIdx.x & 63;
    if (node >= N_NODES) return;
    int r0 = row_off[node];
    int r1 = row_off[node + 1];
    float acc = 0.f;
    int j = r0;
    for (; j + 1 < r1; j += 2) {
        int s0 = col[j];
        int s1 = col[j + 1];
        float v0 = (f < OUT_F) ? h[s0 * OUT_F + f] : 0.f;
        float v1 = (f < OUT_F) ? h[s1 * OUT_F + f] : 0.f;
        acc += v0;
        acc += v1;
    }
    if (j < r1) {
        int s0 = col[j];
        if (f < OUT_F) acc += h[s0 * OUT_F + f];
    }
    if (f < OUT_F)
        out[node * OUT_F + f] = fmaxf(acc + b[f], 0.f);
}

extern "C" void kernel_launch(void* const* d_in, const int* in_sizes, int n_in,
                              void* d_out, int out_size, void* d_ws, size_t ws_size,
                              hipStream_t stream) {
    const float* x  = (const float*)d_in[0];
    const float* W  = (const float*)d_in[1];
    const float* b  = (const float*)d_in[2];
    const int*   ei = (const int*)d_in[3];   // [2, N_EDGES] int32
    float* out = (float*)d_out;

    // workspace layout (256B-aligned slots)
    char* ws = (char*)d_ws;
    float* h        = (float*)(ws);                         // 20,000,000 B
    int*   deg      = (int*)(ws + 20000000);                //    400,000 B
    int*   fill_ctr = (int*)(ws + 20400128);                //    400,000 B
    int*   row_off  = (int*)(ws + 20800256);                //    400,004 B
    int*   bsum     = (int*)(ws + 21200384);                //        784 B
    int*   boff     = (int*)(ws + 21201408);                //        784 B
    int*   col      = (int*)(ws + 21202432);                //  6,400,000 B
    // total ~27.6 MB

    const int T = 256;
    const int n_h = N_NODES * OUT_F;

    // zero deg + fill_ctr (ws arrives poisoned 0xAA)
    hipMemsetAsync(deg, 0, N_NODES * sizeof(int), stream);
    hipMemsetAsync(fill_ctr, 0, N_NODES * sizeof(int), stream);

    gcn_linear_kernel<<<(n_h + T - 1) / T, T, 0, stream>>>(x, W, h);
    gcn_hist_kernel<<<(N_EDGES + T - 1) / T, T, 0, stream>>>(ei, deg);
    gcn_scan1_kernel<<<SCAN_NB, 256, 0, stream>>>(deg, bsum);
    gcn_scan2_kernel<<<1, 256, 0, stream>>>(bsum, boff, row_off);
    gcn_scan3_kernel<<<SCAN_NB, SCAN_CHUNK, 0, stream>>>(deg, boff, row_off);
    gcn_fill_kernel<<<(N_EDGES + T - 1) / T, T, 0, stream>>>(ei, row_off, fill_ctr, col);
    gcn_aggregate_kernel<<<(N_NODES + 3) / 4, 256, 0, stream>>>(h, row_off, col, b, out);
}

// Round 3
// 335.781 us; speedup vs baseline: 1.4891x; 1.1901x over previous
//
#include <hip/hip_runtime.h>

#define N_NODES 100000
#define N_EDGES 1600000
#define IN_F 25
#define OUT_F 50

#define SCAN_CHUNK 512
#define SCAN_NB ((N_NODES + SCAN_CHUNK - 1) / SCAN_CHUNK)   // 196

// ---------- CSR build: histogram of dst ----------
__global__ void gcn_hist_kernel(const int* __restrict__ ei, int* __restrict__ deg) {
    int e = blockIdx.x * blockDim.x + threadIdx.x;
    if (e >= N_EDGES) return;
    atomicAdd(&deg[ei[N_EDGES + e]], 1);
}

// ---------- scan phase 1: per-chunk sums ----------
__global__ void gcn_scan1_kernel(const int* __restrict__ deg, int* __restrict__ bsum) {
    __shared__ int s[256];
    int base = blockIdx.x * SCAN_CHUNK;
    int sum = 0;
    for (int k = 0; k < 2; ++k) {
        int i = base + threadIdx.x + k * 256;
        if (i < N_NODES) sum += deg[i];
    }
    s[threadIdx.x] = sum;
    __syncthreads();
    for (int off = 128; off > 0; off >>= 1) {
        if (threadIdx.x < off) s[threadIdx.x] += s[threadIdx.x + off];
        __syncthreads();
    }
    if (threadIdx.x == 0) bsum[blockIdx.x] = s[0];
}

// ---------- scan phase 2: exclusive scan of chunk sums ----------
__global__ void gcn_scan2_kernel(const int* __restrict__ bsum, int* __restrict__ boff,
                                 int* __restrict__ row_off) {
    __shared__ int s[256];
    int tid = threadIdx.x;
    s[tid] = (tid < SCAN_NB) ? bsum[tid] : 0;
    __syncthreads();
    if (tid == 0) {
        int run = 0;
        for (int i = 0; i < SCAN_NB; ++i) { int v = s[i]; s[i] = run; run += v; }
        row_off[N_NODES] = N_EDGES;
    }
    __syncthreads();
    if (tid < SCAN_NB) boff[tid] = s[tid];
}

// ---------- scan phase 3: exclusive scan within chunk + chunk offset ----------
__global__ void gcn_scan3_kernel(const int* __restrict__ deg, const int* __restrict__ boff,
                                 int* __restrict__ row_off) {
    __shared__ int s[SCAN_CHUNK];
    int tid = threadIdx.x;                 // block = 512 threads
    int i = blockIdx.x * SCAN_CHUNK + tid;
    int v = (i < N_NODES) ? deg[i] : 0;
    s[tid] = v;
    for (int off = 1; off < SCAN_CHUNK; off <<= 1) {
        __syncthreads();
        int t = (tid >= off) ? s[tid - off] : 0;
        __syncthreads();
        s[tid] += t;
    }
    __syncthreads();
    if (i < N_NODES) row_off[i] = boff[blockIdx.x] + s[tid] - v;  // exclusive
}

// ---------- CSR fill ----------
__global__ void gcn_fill_kernel(const int* __restrict__ ei,
                                const int* __restrict__ row_off,
                                int* __restrict__ fill_ctr,
                                int* __restrict__ col) {
    int e = blockIdx.x * blockDim.x + threadIdx.x;
    if (e >= N_EDGES) return;
    int src = ei[e];
    int dst = ei[N_EDGES + e];
    int p = row_off[dst] + atomicAdd(&fill_ctr[dst], 1);
    col[p] = src;
}

// ---------- aggregate x: one HALF-WAVE (32 lanes) per node, lane = input feature ----------
__global__ void gcn_aggregate_x_kernel(const float* __restrict__ x,
                                       const int* __restrict__ row_off,
                                       const int* __restrict__ col,
                                       float* __restrict__ aggx) {
    int node = (blockIdx.x * blockDim.x + threadIdx.x) >> 5;
    int f = threadIdx.x & 31;
    if (node >= N_NODES) return;
    int r0 = row_off[node];
    int r1 = row_off[node + 1];
    int fc = (f < IN_F) ? f : 0;    // safe address for inactive lanes
    float acc = 0.f;
    int j = r0;
    for (; j + 4 <= r1; j += 4) {
        int s0 = col[j];
        int s1 = col[j + 1];
        int s2 = col[j + 2];
        int s3 = col[j + 3];
        float v0 = x[s0 * IN_F + fc];
        float v1 = x[s1 * IN_F + fc];
        float v2 = x[s2 * IN_F + fc];
        float v3 = x[s3 * IN_F + fc];
        acc += v0 + v1;
        acc += v2 + v3;
    }
    for (; j < r1; ++j)
        acc += x[col[j] * IN_F + fc];
    if (f < IN_F)
        aggx[node * IN_F + f] = acc;
}

// ---------- epilogue: out = relu(aggx @ W + b) ----------
__global__ void gcn_out_kernel(const float* __restrict__ aggx,
                               const float* __restrict__ W,
                               const float* __restrict__ b,
                               float* __restrict__ out) {
    __shared__ float Ws[IN_F * OUT_F];
    __shared__ float bs[OUT_F];
    for (int i = threadIdx.x; i < IN_F * OUT_F; i += blockDim.x)
        Ws[i] = W[i];
    for (int i = threadIdx.x; i < OUT_F; i += blockDim.x)
        bs[i] = b[i];
    __syncthreads();
    int idx = blockIdx.x * blockDim.x + threadIdx.x;
    if (idx >= N_NODES * OUT_F) return;
    int n = idx / OUT_F;
    int o = idx - n * OUT_F;
    const float* ar = aggx + n * IN_F;
    float acc = bs[o];
#pragma unroll
    for (int k = 0; k < IN_F; ++k)
        acc += ar[k] * Ws[k * OUT_F + o];
    out[idx] = fmaxf(acc, 0.f);
}

extern "C" void kernel_launch(void* const* d_in, const int* in_sizes, int n_in,
                              void* d_out, int out_size, void* d_ws, size_t ws_size,
                              hipStream_t stream) {
    const float* x  = (const float*)d_in[0];
    const float* W  = (const float*)d_in[1];
    const float* b  = (const float*)d_in[2];
    const int*   ei = (const int*)d_in[3];   // [2, N_EDGES] int32
    float* out = (float*)d_out;

    // workspace layout
    char* ws = (char*)d_ws;
    float* aggx     = (float*)(ws);                 // 10,000,000 B
    int*   deg      = (int*)(ws + 10000128);        //    400,000 B
    int*   fill_ctr = (int*)(ws + 10400384);        //    400,000 B
    int*   row_off  = (int*)(ws + 10800640);        //    400,004 B
    int*   bsum     = (int*)(ws + 11200896);        //        784 B
    int*   boff     = (int*)(ws + 11201792);        //        784 B
    int*   col      = (int*)(ws + 11202688);        //  6,400,000 B
    // total ~17.6 MB

    const int T = 256;
    const int n_out = N_NODES * OUT_F;

    hipMemsetAsync(deg, 0, N_NODES * sizeof(int), stream);
    hipMemsetAsync(fill_ctr, 0, N_NODES * sizeof(int), stream);

    gcn_hist_kernel<<<(N_EDGES + T - 1) / T, T, 0, stream>>>(ei, deg);
    gcn_scan1_kernel<<<SCAN_NB, 256, 0, stream>>>(deg, bsum);
    gcn_scan2_kernel<<<1, 256, 0, stream>>>(bsum, boff, row_off);
    gcn_scan3_kernel<<<SCAN_NB, SCAN_CHUNK, 0, stream>>>(deg, boff, row_off);
    gcn_fill_kernel<<<(N_EDGES + T - 1) / T, T, 0, stream>>>(ei, row_off, fill_ctr, col);
    // aggregate: one half-wave per node -> N_NODES*32 threads
    gcn_aggregate_x_kernel<<<(N_NODES * 32 + T - 1) / T, T, 0, stream>>>(x, row_off, col, aggx);
    gcn_out_kernel<<<(n_out + T - 1) / T, T, 0, stream>>>(aggx, W, b, out);
}